// Round 1
// baseline (510.302 us; speedup 1.0000x reference)
//
#include <hip/hip_runtime.h>

#define FDIM 128

// ---------------- CSR build ----------------

__global__ void count_kernel(const int* __restrict__ dst, int* __restrict__ cnt, int E) {
    int e = blockIdx.x * blockDim.x + threadIdx.x;
    if (e < E) atomicAdd(&cnt[dst[e]], 1);
}

// Single-block hierarchical exclusive scan over n counts -> off[0..n], cur[0..n-1]
__global__ void scan_kernel(const int* __restrict__ cnt, int* __restrict__ off,
                            int* __restrict__ cur, int n) {
    __shared__ int wsum[16];
    const int lane = threadIdx.x & 63;
    const int wid  = threadIdx.x >> 6;
    int carry = 0;
    for (int base = 0; base < n; base += 1024) {
        int i = base + (int)threadIdx.x;
        int v = (i < n) ? cnt[i] : 0;
        // wave-level inclusive scan
        int incl = v;
        #pragma unroll
        for (int d = 1; d < 64; d <<= 1) {
            int t = __shfl_up(incl, d);
            if (lane >= d) incl += t;
        }
        if (lane == 63) wsum[wid] = incl;
        __syncthreads();
        if (wid == 0) {
            int s = (lane < 16) ? wsum[lane] : 0;
            #pragma unroll
            for (int d = 1; d < 16; d <<= 1) {
                int t = __shfl_up(s, d);
                if (lane >= d) s += t;
            }
            if (lane < 16) wsum[lane] = s;
        }
        __syncthreads();
        int wbase = wid ? wsum[wid - 1] : 0;
        int excl  = carry + wbase + incl - v;
        if (i < n) { off[i] = excl; cur[i] = excl; }
        int tile_total = wsum[15];
        __syncthreads();           // wsum reused next tile
        carry += tile_total;
    }
    if (threadIdx.x == 0) off[n] = carry;
}

__global__ void scatter_kernel(const int* __restrict__ src, const int* __restrict__ dst,
                               int* __restrict__ cur, int* __restrict__ csr, int E) {
    int e = blockIdx.x * blockDim.x + threadIdx.x;
    if (e < E) {
        int pos = atomicAdd(&cur[dst[e]], 1);
        csr[pos] = src[e];
    }
}

// ---------------- mean aggregation: one wave per node ----------------

__global__ void agg_kernel(const float* __restrict__ feat, const int* __restrict__ off,
                           const int* __restrict__ csr, float* __restrict__ agg, int n) {
    int node = blockIdx.x * (blockDim.x >> 6) + (threadIdx.x >> 6);
    if (node >= n) return;
    const int lane = threadIdx.x & 63;
    const int j0 = off[node], j1 = off[node + 1];
    float a0 = 0.f, a1 = 0.f;
    int j = j0;
    for (; j + 1 < j1; j += 2) {
        int s0 = csr[j], s1 = csr[j + 1];
        float2 v0 = *(const float2*)(feat + (size_t)s0 * FDIM + lane * 2);
        float2 v1 = *(const float2*)(feat + (size_t)s1 * FDIM + lane * 2);
        a0 += v0.x + v1.x;
        a1 += v0.y + v1.y;
    }
    if (j < j1) {
        int s0 = csr[j];
        float2 v0 = *(const float2*)(feat + (size_t)s0 * FDIM + lane * 2);
        a0 += v0.x; a1 += v0.y;
    }
    float inv = 1.0f / fmaxf((float)(j1 - j0), 1.0f);
    float2 o; o.x = a0 * inv; o.y = a1 * inv;
    *(float2*)(agg + (size_t)node * FDIM + lane * 2) = o;
}

// ---------------- fused SAGE linear: out = relu(agg@Wl^T + x@Wr^T + b) ----------------
// block = 256 threads, 32-row tile, thread = (col c in 0..127, row-half rh in 0..1)

template<int RELU>
__global__ void sage_linear_kernel(const float* __restrict__ agg, const float* __restrict__ xin,
                                   const float* __restrict__ Wl, const float* __restrict__ Wr,
                                   const float* __restrict__ bias, float* __restrict__ out, int n) {
    __shared__ float As[32][FDIM];
    __shared__ float Xs[32][FDIM];
    const int row0 = blockIdx.x * 32;
    const int c  = threadIdx.x & 127;
    const int rh = threadIdx.x >> 7;   // 0 or 1

    for (int r = rh; r < 32; r += 2) {
        int row = row0 + r;
        if (row < n) {
            As[r][c] = agg[(size_t)row * FDIM + c];
            Xs[r][c] = xin[(size_t)row * FDIM + c];
        } else {
            As[r][c] = 0.f; Xs[r][c] = 0.f;
        }
    }
    __syncthreads();

    float acc[16];
    #pragma unroll
    for (int r = 0; r < 16; ++r) acc[r] = 0.f;

    const float* wlrow = Wl + (size_t)c * FDIM;
    const float* wrrow = Wr + (size_t)c * FDIM;
    for (int k = 0; k < FDIM; k += 4) {
        float4 wl4 = *(const float4*)(wlrow + k);
        float4 wr4 = *(const float4*)(wrrow + k);
        #pragma unroll
        for (int r = 0; r < 16; ++r) {
            float4 a4 = *(const float4*)(&As[rh * 16 + r][k]);
            float4 x4 = *(const float4*)(&Xs[rh * 16 + r][k]);
            acc[r] += a4.x * wl4.x + a4.y * wl4.y + a4.z * wl4.z + a4.w * wl4.w
                    + x4.x * wr4.x + x4.y * wr4.y + x4.z * wr4.z + x4.w * wr4.w;
        }
    }
    float bc = bias[c];
    #pragma unroll
    for (int r = 0; r < 16; ++r) {
        int row = row0 + rh * 16 + r;
        if (row < n) {
            float v = acc[r] + bc;
            out[(size_t)row * FDIM + c] = RELU ? fmaxf(v, 0.f) : v;
        }
    }
}

// ---------------- final: out = h @ W3^T + b3  (64 cols) ----------------

__global__ void final_kernel(const float* __restrict__ h, const float* __restrict__ W3,
                             const float* __restrict__ b3, float* __restrict__ out, int n) {
    __shared__ float Hs[32][FDIM];
    const int row0 = blockIdx.x * 32;
    const int c  = threadIdx.x & 63;    // output col
    const int rg = threadIdx.x >> 6;    // 0..3 -> rows rg*8 .. rg*8+7
    const int tc = threadIdx.x & 127;
    const int th = threadIdx.x >> 7;

    for (int r = th; r < 32; r += 2) {
        int row = row0 + r;
        Hs[r][tc] = (row < n) ? h[(size_t)row * FDIM + tc] : 0.f;
    }
    __syncthreads();

    float acc[8];
    #pragma unroll
    for (int r = 0; r < 8; ++r) acc[r] = 0.f;

    const float* wrow = W3 + (size_t)c * FDIM;
    for (int k = 0; k < FDIM; k += 4) {
        float4 w4 = *(const float4*)(wrow + k);
        #pragma unroll
        for (int r = 0; r < 8; ++r) {
            float4 h4 = *(const float4*)(&Hs[rg * 8 + r][k]);
            acc[r] += h4.x * w4.x + h4.y * w4.y + h4.z * w4.z + h4.w * w4.w;
        }
    }
    float bc = b3[c];
    #pragma unroll
    for (int r = 0; r < 8; ++r) {
        int row = row0 + rg * 8 + r;
        if (row < n) out[(size_t)row * 64 + c] = acc[r] + bc;
    }
}

// ---------------- launch ----------------

extern "C" void kernel_launch(void* const* d_in, const int* in_sizes, int n_in,
                              void* d_out, int out_size, void* d_ws, size_t ws_size,
                              hipStream_t stream) {
    const float* x   = (const float*)d_in[0];
    const int*   ei  = (const int*)d_in[1];
    const float* W1l = (const float*)d_in[2];
    const float* b1  = (const float*)d_in[3];
    const float* W1r = (const float*)d_in[4];
    const float* W2l = (const float*)d_in[5];
    const float* b2  = (const float*)d_in[6];
    const float* W2r = (const float*)d_in[7];
    const float* W3  = (const float*)d_in[8];
    const float* b3  = (const float*)d_in[9];
    float* out = (float*)d_out;

    const int N = in_sizes[0] / FDIM;   // 50000
    const int E = in_sizes[1] / 2;      // 800000
    const int* src = ei;
    const int* dst = ei + E;

    char* ws = (char*)d_ws;
    size_t p = 0;
    auto alloc = [&](size_t bytes) {
        char* q = ws + p;
        p += (bytes + 255) & ~(size_t)255;
        return q;
    };
    int* cnt   = (int*)alloc((size_t)N * 4);
    int* off   = (int*)alloc((size_t)(N + 1) * 4);
    int* cur   = (int*)alloc((size_t)N * 4);
    int* csr   = (int*)alloc((size_t)E * 4);
    float* agg = (float*)alloc((size_t)N * FDIM * 4);
    float* h1  = (float*)alloc((size_t)N * FDIM * 4);
    float* h2  = (float*)alloc((size_t)N * FDIM * 4);

    hipMemsetAsync(cnt, 0, (size_t)N * 4, stream);
    count_kernel<<<(E + 255) / 256, 256, 0, stream>>>(dst, cnt, E);
    scan_kernel<<<1, 1024, 0, stream>>>(cnt, off, cur, N);
    scatter_kernel<<<(E + 255) / 256, 256, 0, stream>>>(src, dst, cur, csr, E);

    // layer 1
    agg_kernel<<<(N + 3) / 4, 256, 0, stream>>>(x, off, csr, agg, N);
    sage_linear_kernel<1><<<(N + 31) / 32, 256, 0, stream>>>(agg, x, W1l, W1r, b1, h1, N);
    // layer 2
    agg_kernel<<<(N + 3) / 4, 256, 0, stream>>>(h1, off, csr, agg, N);
    sage_linear_kernel<1><<<(N + 31) / 32, 256, 0, stream>>>(agg, h1, W2l, W2r, b2, h2, N);
    // head
    final_kernel<<<(N + 31) / 32, 256, 0, stream>>>(h2, W3, b3, out, N);
}

// Round 2
// 308.444 us; speedup vs baseline: 1.6544x; 1.6544x over previous
//
#include <hip/hip_runtime.h>

#define FDIM 128

typedef __attribute__((ext_vector_type(8))) short bf16x8;
typedef __attribute__((ext_vector_type(4))) float f32x4;

static __device__ __forceinline__ ushort f2bf(float f) {
    uint u = __float_as_uint(f);
    uint r = (u + 0x7FFF + ((u >> 16) & 1)) >> 16;
    return (ushort)r;
}
static __device__ __forceinline__ uint packbf(float lo, float hi) {
    return (uint)f2bf(lo) | ((uint)f2bf(hi) << 16);
}
static __device__ __forceinline__ float bflo(uint v) { return __uint_as_float(v << 16); }
static __device__ __forceinline__ float bfhi(uint v) { return __uint_as_float(v & 0xFFFF0000u); }

// ---------------- CSR build ----------------

__global__ void count_kernel(const int* __restrict__ dst, int* __restrict__ cnt, int E) {
    int e = blockIdx.x * blockDim.x + threadIdx.x;
    if (e < E) atomicAdd(&cnt[dst[e]], 1);
}

__global__ void scan_kernel(const int* __restrict__ cnt, int* __restrict__ off,
                            int* __restrict__ cur, int n) {
    __shared__ int wsum[16];
    const int lane = threadIdx.x & 63;
    const int wid  = threadIdx.x >> 6;
    int carry = 0;
    for (int base = 0; base < n; base += 1024) {
        int i = base + (int)threadIdx.x;
        int v = (i < n) ? cnt[i] : 0;
        int incl = v;
        #pragma unroll
        for (int d = 1; d < 64; d <<= 1) {
            int t = __shfl_up(incl, d);
            if (lane >= d) incl += t;
        }
        if (lane == 63) wsum[wid] = incl;
        __syncthreads();
        if (wid == 0) {
            int s = (lane < 16) ? wsum[lane] : 0;
            #pragma unroll
            for (int d = 1; d < 16; d <<= 1) {
                int t = __shfl_up(s, d);
                if (lane >= d) s += t;
            }
            if (lane < 16) wsum[lane] = s;
        }
        __syncthreads();
        int wbase = wid ? wsum[wid - 1] : 0;
        int excl  = carry + wbase + incl - v;
        if (i < n) { off[i] = excl; cur[i] = excl; }
        int tile_total = wsum[15];
        __syncthreads();
        carry += tile_total;
    }
    if (threadIdx.x == 0) off[n] = carry;
}

__global__ void scatter_kernel(const int* __restrict__ src, const int* __restrict__ dst,
                               int* __restrict__ cur, int* __restrict__ csr, int E) {
    int e = blockIdx.x * blockDim.x + threadIdx.x;
    if (e < E) {
        int pos = atomicAdd(&cur[dst[e]], 1);
        csr[pos] = src[e];
    }
}

// ---------------- fp32 -> bf16 conversions ----------------

__global__ void convert_x_kernel(const float* __restrict__ src, ushort* __restrict__ dst, int n8) {
    int i = blockIdx.x * blockDim.x + threadIdx.x;
    if (i >= n8) return;
    const float* s = src + (size_t)i * 8;
    float4 a = *(const float4*)(s);
    float4 b = *(const float4*)(s + 4);
    uint4 o;
    o.x = packbf(a.x, a.y); o.y = packbf(a.z, a.w);
    o.z = packbf(b.x, b.y); o.w = packbf(b.z, b.w);
    *(uint4*)(dst + (size_t)i * 8) = o;
}

__global__ void convert_w_kernel(const float* W1l, const float* W1r,
                                 const float* W2l, const float* W2r, const float* W3,
                                 ushort* w1l, ushort* w1r, ushort* w2l, ushort* w2r, ushort* w3) {
    int i = blockIdx.x * blockDim.x + threadIdx.x;   // 0..2047, each does 8 elems
    if (i >= 2048) return;
    const float* srcs[5] = {W1l, W1r, W2l, W2r, W3};
    ushort* dsts[5] = {w1l, w1r, w2l, w2r, w3};
    #pragma unroll
    for (int m = 0; m < 5; ++m) {
        if (m == 4 && i >= 1024) break;
        const float* s = srcs[m] + (size_t)i * 8;
        float4 a = *(const float4*)(s);
        float4 b = *(const float4*)(s + 4);
        uint4 o;
        o.x = packbf(a.x, a.y); o.y = packbf(a.z, a.w);
        o.z = packbf(b.x, b.y); o.w = packbf(b.z, b.w);
        *(uint4*)(dsts[m] + (size_t)i * 8) = o;
    }
}

// ---------------- mean aggregation (bf16 in/out, fp32 accum): one wave per node ----------------

__global__ void agg_bf16_kernel(const ushort* __restrict__ feat, const int* __restrict__ off,
                                const int* __restrict__ csr, ushort* __restrict__ agg, int n) {
    int node = blockIdx.x * (blockDim.x >> 6) + (threadIdx.x >> 6);
    if (node >= n) return;
    const int lane = threadIdx.x & 63;
    const int j0 = off[node], j1 = off[node + 1];
    float a0 = 0.f, a1 = 0.f;
    int j = j0;
    for (; j + 3 < j1; j += 4) {
        int s0 = csr[j], s1 = csr[j + 1], s2 = csr[j + 2], s3 = csr[j + 3];
        uint v0 = *(const uint*)(feat + (size_t)s0 * FDIM + lane * 2);
        uint v1 = *(const uint*)(feat + (size_t)s1 * FDIM + lane * 2);
        uint v2 = *(const uint*)(feat + (size_t)s2 * FDIM + lane * 2);
        uint v3 = *(const uint*)(feat + (size_t)s3 * FDIM + lane * 2);
        a0 += bflo(v0) + bflo(v1) + bflo(v2) + bflo(v3);
        a1 += bfhi(v0) + bfhi(v1) + bfhi(v2) + bfhi(v3);
    }
    for (; j < j1; ++j) {
        uint v0 = *(const uint*)(feat + (size_t)csr[j] * FDIM + lane * 2);
        a0 += bflo(v0); a1 += bfhi(v0);
    }
    float inv = 1.0f / fmaxf((float)(j1 - j0), 1.0f);
    *(uint*)(agg + (size_t)node * FDIM + lane * 2) = packbf(a0 * inv, a1 * inv);
}

// ---------------- MFMA SAGE linear: out = relu(agg@Wl^T + x@Wr^T + b), bf16 ----------------
// block = 256 thr (4 waves). 32 rows x 128 cols per block.
// wave w: rows 16*(w&1).., cols 64*(w>>1).. (4 col-tiles of 16).
// LDS tiles XOR-swizzled in 16B chunks: chunk' = chunk ^ (row&7).

template<int RELU>
__global__ void sage_linear_mfma(const ushort* __restrict__ agg, const ushort* __restrict__ xin,
                                 const ushort* __restrict__ Wl, const ushort* __restrict__ Wr,
                                 const float* __restrict__ bias, ushort* __restrict__ out, int n) {
    __shared__ __align__(16) ushort As[32 * FDIM];
    __shared__ __align__(16) ushort Xs[32 * FDIM];
    const int row0 = blockIdx.x * 32;
    const int lane = threadIdx.x & 63;
    const int wid  = threadIdx.x >> 6;
    const int wrow = wid & 1;        // row-group 0/1
    const int wcol = wid >> 1;       // col-group 0/1 (64 cols each)

    // stage 32x128 of agg and x (bf16), swizzled
    const float4 z4 = make_float4(0.f, 0.f, 0.f, 0.f);
    #pragma unroll
    for (int i = 0; i < 2; ++i) {
        int s = threadIdx.x + i * 256;      // 0..511
        int r = s >> 4, cch = s & 15;
        int row = row0 + r;
        float4 va = z4, vx = z4;
        if (row < n) {
            va = *(const float4*)(agg + (size_t)row * FDIM + cch * 8);
            vx = *(const float4*)(xin + (size_t)row * FDIM + cch * 8);
        }
        int sc = cch ^ (r & 7);
        *(float4*)(As + (r * 16 + sc) * 8) = va;
        *(float4*)(Xs + (r * 16 + sc) * 8) = vx;
    }
    __syncthreads();

    const int lr = lane & 15;        // fragment 16-dim index
    const int lk = lane >> 4;        // k-chunk 0..3

    f32x4 acc[4];
    #pragma unroll
    for (int t = 0; t < 4; ++t) acc[t] = (f32x4){0.f, 0.f, 0.f, 0.f};

    const int arow = wrow * 16 + lr;
    #pragma unroll
    for (int ks = 0; ks < 4; ++ks) {
        bf16x8 a = *(const bf16x8*)(As + (arow * 16 + ((ks * 4 + lk) ^ (arow & 7))) * 8);
        #pragma unroll
        for (int t = 0; t < 4; ++t) {
            int wr = wcol * 64 + t * 16 + lr;
            bf16x8 b = *(const bf16x8*)(Wl + (size_t)wr * FDIM + ks * 32 + lk * 8);
            acc[t] = __builtin_amdgcn_mfma_f32_16x16x32_bf16(a, b, acc[t], 0, 0, 0);
        }
    }
    #pragma unroll
    for (int ks = 0; ks < 4; ++ks) {
        bf16x8 a = *(const bf16x8*)(Xs + (arow * 16 + ((ks * 4 + lk) ^ (arow & 7))) * 8);
        #pragma unroll
        for (int t = 0; t < 4; ++t) {
            int wr = wcol * 64 + t * 16 + lr;
            bf16x8 b = *(const bf16x8*)(Wr + (size_t)wr * FDIM + ks * 32 + lk * 8);
            acc[t] = __builtin_amdgcn_mfma_f32_16x16x32_bf16(a, b, acc[t], 0, 0, 0);
        }
    }

    #pragma unroll
    for (int t = 0; t < 4; ++t) {
        int col = wcol * 64 + t * 16 + lr;
        float bc = bias[col];
        #pragma unroll
        for (int j = 0; j < 4; ++j) {
            int row = row0 + wrow * 16 + lk * 4 + j;
            if (row < n) {
                float v = acc[t][j] + bc;
                if (RELU) v = fmaxf(v, 0.f);
                out[(size_t)row * FDIM + col] = f2bf(v);
            }
        }
    }
}

// ---------------- MFMA head: out = h @ W3^T + b3 (fp32 out, 64 cols) ----------------

__global__ void final_mfma(const ushort* __restrict__ h, const ushort* __restrict__ W3,
                           const float* __restrict__ b3, float* __restrict__ out, int n) {
    __shared__ __align__(16) ushort Hs[32 * FDIM];
    const int row0 = blockIdx.x * 32;
    const int lane = threadIdx.x & 63;
    const int wid  = threadIdx.x >> 6;
    const int wrow = wid & 1;
    const int wcol = wid >> 1;       // 32 cols each

    const float4 z4 = make_float4(0.f, 0.f, 0.f, 0.f);
    #pragma unroll
    for (int i = 0; i < 2; ++i) {
        int s = threadIdx.x + i * 256;
        int r = s >> 4, cch = s & 15;
        int row = row0 + r;
        float4 vh = (row < n) ? *(const float4*)(h + (size_t)row * FDIM + cch * 8) : z4;
        int sc = cch ^ (r & 7);
        *(float4*)(Hs + (r * 16 + sc) * 8) = vh;
    }
    __syncthreads();

    const int lr = lane & 15;
    const int lk = lane >> 4;

    f32x4 acc[2];
    #pragma unroll
    for (int t = 0; t < 2; ++t) acc[t] = (f32x4){0.f, 0.f, 0.f, 0.f};

    const int arow = wrow * 16 + lr;
    #pragma unroll
    for (int ks = 0; ks < 4; ++ks) {
        bf16x8 a = *(const bf16x8*)(Hs + (arow * 16 + ((ks * 4 + lk) ^ (arow & 7))) * 8);
        #pragma unroll
        for (int t = 0; t < 2; ++t) {
            int wr = wcol * 32 + t * 16 + lr;
            bf16x8 b = *(const bf16x8*)(W3 + (size_t)wr * FDIM + ks * 32 + lk * 8);
            acc[t] = __builtin_amdgcn_mfma_f32_16x16x32_bf16(a, b, acc[t], 0, 0, 0);
        }
    }

    #pragma unroll
    for (int t = 0; t < 2; ++t) {
        int col = wcol * 32 + t * 16 + lr;
        float bc = b3[col];
        #pragma unroll
        for (int j = 0; j < 4; ++j) {
            int row = row0 + wrow * 16 + lk * 4 + j;
            if (row < n) out[(size_t)row * 64 + col] = acc[t][j] + bc;
        }
    }
}

// ---------------- launch ----------------

extern "C" void kernel_launch(void* const* d_in, const int* in_sizes, int n_in,
                              void* d_out, int out_size, void* d_ws, size_t ws_size,
                              hipStream_t stream) {
    const float* x   = (const float*)d_in[0];
    const int*   ei  = (const int*)d_in[1];
    const float* W1l = (const float*)d_in[2];
    const float* b1  = (const float*)d_in[3];
    const float* W1r = (const float*)d_in[4];
    const float* W2l = (const float*)d_in[5];
    const float* b2  = (const float*)d_in[6];
    const float* W2r = (const float*)d_in[7];
    const float* W3  = (const float*)d_in[8];
    const float* b3  = (const float*)d_in[9];
    float* out = (float*)d_out;

    const int N = in_sizes[0] / FDIM;   // 50000
    const int E = in_sizes[1] / 2;      // 800000
    const int* src = ei;
    const int* dst = ei + E;

    char* ws = (char*)d_ws;
    size_t p = 0;
    auto alloc = [&](size_t bytes) {
        char* q = ws + p;
        p += (bytes + 255) & ~(size_t)255;
        return q;
    };
    int* cnt    = (int*)alloc((size_t)N * 4);
    int* off    = (int*)alloc((size_t)(N + 1) * 4);
    int* cur    = (int*)alloc((size_t)N * 4);
    int* csr    = (int*)alloc((size_t)E * 4);
    ushort* xb  = (ushort*)alloc((size_t)N * FDIM * 2);
    ushort* agb = (ushort*)alloc((size_t)N * FDIM * 2);
    ushort* h1b = (ushort*)alloc((size_t)N * FDIM * 2);
    ushort* h2b = (ushort*)alloc((size_t)N * FDIM * 2);
    ushort* w1l = (ushort*)alloc(16384 * 2);
    ushort* w1r = (ushort*)alloc(16384 * 2);
    ushort* w2l = (ushort*)alloc(16384 * 2);
    ushort* w2r = (ushort*)alloc(16384 * 2);
    ushort* w3  = (ushort*)alloc(8192 * 2);

    hipMemsetAsync(cnt, 0, (size_t)N * 4, stream);
    count_kernel<<<(E + 255) / 256, 256, 0, stream>>>(dst, cnt, E);
    scan_kernel<<<1, 1024, 0, stream>>>(cnt, off, cur, N);
    scatter_kernel<<<(E + 255) / 256, 256, 0, stream>>>(src, dst, cur, csr, E);

    convert_x_kernel<<<(N * FDIM / 8 + 255) / 256, 256, 0, stream>>>(x, xb, N * FDIM / 8);
    convert_w_kernel<<<8, 256, 0, stream>>>(W1l, W1r, W2l, W2r, W3, w1l, w1r, w2l, w2r, w3);

    const int lgrid = (N + 31) / 32;
    // layer 1
    agg_bf16_kernel<<<(N + 3) / 4, 256, 0, stream>>>(xb, off, csr, agb, N);
    sage_linear_mfma<1><<<lgrid, 256, 0, stream>>>(agb, xb, w1l, w1r, b1, h1b, N);
    // layer 2
    agg_bf16_kernel<<<(N + 3) / 4, 256, 0, stream>>>(h1b, off, csr, agb, N);
    sage_linear_mfma<1><<<lgrid, 256, 0, stream>>>(agb, h1b, w2l, w2r, b2, h2b, N);
    // head
    final_mfma<<<lgrid, 256, 0, stream>>>(h2b, w3, b3, out, N);
}

// Round 3
// 199.701 us; speedup vs baseline: 2.5553x; 1.5445x over previous
//
#include <hip/hip_runtime.h>

#define FDIM 128

typedef __attribute__((ext_vector_type(8))) short bf16x8;
typedef __attribute__((ext_vector_type(4))) float f32x4;

static __device__ __forceinline__ ushort f2bf(float f) {
    uint u = __float_as_uint(f);
    uint r = (u + 0x7FFF + ((u >> 16) & 1)) >> 16;
    return (ushort)r;
}
static __device__ __forceinline__ uint packbf(float lo, float hi) {
    return (uint)f2bf(lo) | ((uint)f2bf(hi) << 16);
}
static __device__ __forceinline__ float bflo(uint v) { return __uint_as_float(v << 16); }
static __device__ __forceinline__ float bfhi(uint v) { return __uint_as_float(v & 0xFFFF0000u); }

// ---------------- prep: convert x + weights to bf16, bucket histogram ----------------
// grid: [0,NCONV) convert x | [NCONV,NCONV+36) convert weights | [NCONV+36, +NHIST) histogram

__global__ void prep_kernel(const float* __restrict__ x, ushort* __restrict__ xb, int nx8,
                            const float* __restrict__ W1l, const float* __restrict__ W1r,
                            const float* __restrict__ W2l, const float* __restrict__ W2r,
                            const float* __restrict__ W3, ushort* __restrict__ wbuf,
                            const int* __restrict__ dst, int E, int* __restrict__ bcnt,
                            int nconv) {
    const int b = blockIdx.x;
    const int tid = threadIdx.x;
    if (b < nconv) {
        int i = b * 256 + tid;
        if (i < nx8) {
            const float* s = x + (size_t)i * 8;
            float4 a = *(const float4*)(s);
            float4 c = *(const float4*)(s + 4);
            uint4 o;
            o.x = packbf(a.x, a.y); o.y = packbf(a.z, a.w);
            o.z = packbf(c.x, c.y); o.w = packbf(c.z, c.w);
            *(uint4*)(xb + (size_t)i * 8) = o;
        }
    } else if (b < nconv + 36) {
        int c = (b - nconv) * 256 + tid;      // 0..9215 chunks of 8
        const float* s; ushort* d;
        if (c < 2048)      { s = W1l + (size_t)c * 8;          d = wbuf + (size_t)c * 8; }
        else if (c < 4096) { s = W1r + (size_t)(c - 2048) * 8; d = wbuf + 16384 + (size_t)(c - 2048) * 8; }
        else if (c < 6144) { s = W2l + (size_t)(c - 4096) * 8; d = wbuf + 32768 + (size_t)(c - 4096) * 8; }
        else if (c < 8192) { s = W2r + (size_t)(c - 6144) * 8; d = wbuf + 49152 + (size_t)(c - 6144) * 8; }
        else               { s = W3  + (size_t)(c - 8192) * 8; d = wbuf + 65536 + (size_t)(c - 8192) * 8; }
        float4 a = *(const float4*)(s);
        float4 cc = *(const float4*)(s + 4);
        uint4 o;
        o.x = packbf(a.x, a.y); o.y = packbf(a.z, a.w);
        o.z = packbf(cc.x, cc.y); o.w = packbf(cc.z, cc.w);
        *(uint4*)d = o;
    } else {
        __shared__ int lh[256];
        int hb = b - nconv - 36;
        lh[tid] = 0;
        __syncthreads();
        #pragma unroll
        for (int k = 0; k < 8; ++k) {
            int e = hb * 2048 + k * 256 + tid;
            if (e < E) atomicAdd(&lh[dst[e] >> 8], 1);
        }
        __syncthreads();
        if (lh[tid]) atomicAdd(&bcnt[tid], lh[tid]);
    }
}

// ---------------- scan 196 bucket counts (1 block, 64 threads) ----------------

__global__ void scan_buckets(const int* __restrict__ bcnt, int* __restrict__ bbase,
                             int* __restrict__ bcur, int nb) {
    const int lane = threadIdx.x;
    const int i0 = lane * 4;
    int v0 = (i0 + 0 < nb) ? bcnt[i0 + 0] : 0;
    int v1 = (i0 + 1 < nb) ? bcnt[i0 + 1] : 0;
    int v2 = (i0 + 2 < nb) ? bcnt[i0 + 2] : 0;
    int v3 = (i0 + 3 < nb) ? bcnt[i0 + 3] : 0;
    int s = v0 + v1 + v2 + v3;
    int incl = s;
    #pragma unroll
    for (int d = 1; d < 64; d <<= 1) {
        int t = __shfl_up(incl, d);
        if (lane >= d) incl += t;
    }
    int excl = incl - s;
    int e0 = excl, e1 = excl + v0, e2 = e1 + v1, e3 = e2 + v2;
    if (i0 + 0 < nb) { bbase[i0 + 0] = e0; bcur[i0 + 0] = e0; }
    if (i0 + 1 < nb) { bbase[i0 + 1] = e1; bcur[i0 + 1] = e1; }
    if (i0 + 2 < nb) { bbase[i0 + 2] = e2; bcur[i0 + 2] = e2; }
    if (i0 + 3 < nb) { bbase[i0 + 3] = e3; bcur[i0 + 3] = e3; }
    int total = __shfl(incl, 63);
    if (lane == 0) bbase[nb] = total;
}

// ---------------- bin edges into bucket-contiguous (src,dst) pairs ----------------

__global__ void pair_scatter(const int* __restrict__ src, const int* __restrict__ dst,
                             int* __restrict__ bcur, uint2* __restrict__ pairs, int E) {
    __shared__ int lh[256];
    __shared__ int gb[256];
    const int tid = threadIdx.x;
    lh[tid] = 0;
    __syncthreads();
    int ss[8], dd[8], sl[8];
    #pragma unroll
    for (int k = 0; k < 8; ++k) {
        int e = blockIdx.x * 2048 + k * 256 + tid;
        if (e < E) {
            ss[k] = src[e];
            dd[k] = dst[e];
            sl[k] = atomicAdd(&lh[dd[k] >> 8], 1);
        } else dd[k] = -1;
    }
    __syncthreads();
    if (lh[tid]) gb[tid] = atomicAdd(&bcur[tid], lh[tid]);
    __syncthreads();
    #pragma unroll
    for (int k = 0; k < 8; ++k) {
        if (dd[k] >= 0) pairs[gb[dd[k] >> 8] + sl[k]] = make_uint2((uint)ss[k], (uint)dd[k]);
    }
}

// ---------------- per-bucket CSR: LDS count/scan/scatter ----------------

__global__ void bucket_csr(const uint2* __restrict__ pairs, const int* __restrict__ bbase,
                           int* __restrict__ off, int* __restrict__ csr, int N) {
    __shared__ int cnt[256];
    __shared__ int base[256];
    __shared__ int cur[256];
    const int b = blockIdx.x;
    const int tid = threadIdx.x;
    const int p0 = bbase[b], p1 = bbase[b + 1];
    cnt[tid] = 0;
    __syncthreads();
    for (int p = p0 + tid; p < p1; p += 256) atomicAdd(&cnt[pairs[p].y & 255], 1);
    __syncthreads();
    if (tid < 64) {
        int i0 = tid * 4;
        int v0 = cnt[i0], v1 = cnt[i0 + 1], v2 = cnt[i0 + 2], v3 = cnt[i0 + 3];
        int s = v0 + v1 + v2 + v3;
        int incl = s;
        #pragma unroll
        for (int d = 1; d < 64; d <<= 1) {
            int t = __shfl_up(incl, d);
            if (tid >= d) incl += t;
        }
        int excl = incl - s;
        base[i0] = excl; base[i0 + 1] = excl + v0;
        base[i0 + 2] = excl + v0 + v1; base[i0 + 3] = excl + v0 + v1 + v2;
        cur[i0] = base[i0]; cur[i0 + 1] = base[i0 + 1];
        cur[i0 + 2] = base[i0 + 2]; cur[i0 + 3] = base[i0 + 3];
    }
    __syncthreads();
    int node = (b << 8) + tid;
    if (node <= N) off[node] = p0 + base[tid];
    for (int p = p0 + tid; p < p1; p += 256) {
        uint2 e = pairs[p];
        int slot = atomicAdd(&cur[e.y & 255], 1);
        csr[p0 + slot] = (int)e.x;
    }
}

// ---------------- mean aggregation: wave/node, 4 neighbors x 16B chunks ----------------

__global__ void agg_kernel(const ushort* __restrict__ feat, const int* __restrict__ off,
                           const int* __restrict__ csr, ushort* __restrict__ agg, int n) {
    int node = blockIdx.x * 4 + (threadIdx.x >> 6);
    if (node >= n) return;
    const int lane = threadIdx.x & 63;
    const int g = lane >> 4;       // neighbor slot 0..3
    const int c = lane & 15;       // 16B chunk 0..15
    const int j0 = off[node], j1 = off[node + 1];
    float a[8] = {0.f, 0.f, 0.f, 0.f, 0.f, 0.f, 0.f, 0.f};
    for (int j = j0 + g; j < j1; j += 4) {
        int s = csr[j];
        uint4 v = *(const uint4*)(feat + (size_t)s * FDIM + c * 8);
        a[0] += bflo(v.x); a[1] += bfhi(v.x);
        a[2] += bflo(v.y); a[3] += bfhi(v.y);
        a[4] += bflo(v.z); a[5] += bfhi(v.z);
        a[6] += bflo(v.w); a[7] += bfhi(v.w);
    }
    #pragma unroll
    for (int k = 0; k < 8; ++k) {
        a[k] += __shfl_xor(a[k], 16);
        a[k] += __shfl_xor(a[k], 32);
    }
    if (g == 0) {
        float inv = 1.0f / fmaxf((float)(j1 - j0), 1.0f);
        uint4 o;
        o.x = packbf(a[0] * inv, a[1] * inv);
        o.y = packbf(a[2] * inv, a[3] * inv);
        o.z = packbf(a[4] * inv, a[5] * inv);
        o.w = packbf(a[6] * inv, a[7] * inv);
        *(uint4*)(agg + (size_t)node * FDIM + c * 8) = o;
    }
}

// ---------------- MFMA SAGE linear: out = relu(agg@Wl^T + x@Wr^T + b), bf16 ----------------

template<int RELU>
__global__ void sage_linear_mfma(const ushort* __restrict__ agg, const ushort* __restrict__ xin,
                                 const ushort* __restrict__ Wl, const ushort* __restrict__ Wr,
                                 const float* __restrict__ bias, ushort* __restrict__ out, int n) {
    __shared__ __align__(16) ushort As[32 * FDIM];
    __shared__ __align__(16) ushort Xs[32 * FDIM];
    const int row0 = blockIdx.x * 32;
    const int lane = threadIdx.x & 63;
    const int wid  = threadIdx.x >> 6;
    const int wrow = wid & 1;
    const int wcol = wid >> 1;

    const float4 z4 = make_float4(0.f, 0.f, 0.f, 0.f);
    #pragma unroll
    for (int i = 0; i < 2; ++i) {
        int s = threadIdx.x + i * 256;
        int r = s >> 4, cch = s & 15;
        int row = row0 + r;
        float4 va = z4, vx = z4;
        if (row < n) {
            va = *(const float4*)(agg + (size_t)row * FDIM + cch * 8);
            vx = *(const float4*)(xin + (size_t)row * FDIM + cch * 8);
        }
        int sc = cch ^ (r & 7);
        *(float4*)(As + (r * 16 + sc) * 8) = va;
        *(float4*)(Xs + (r * 16 + sc) * 8) = vx;
    }
    __syncthreads();

    const int lr = lane & 15;
    const int lk = lane >> 4;

    f32x4 acc[4];
    #pragma unroll
    for (int t = 0; t < 4; ++t) acc[t] = (f32x4){0.f, 0.f, 0.f, 0.f};

    const int arow = wrow * 16 + lr;
    #pragma unroll
    for (int ks = 0; ks < 4; ++ks) {
        bf16x8 a = *(const bf16x8*)(As + (arow * 16 + ((ks * 4 + lk) ^ (arow & 7))) * 8);
        #pragma unroll
        for (int t = 0; t < 4; ++t) {
            int wr = wcol * 64 + t * 16 + lr;
            bf16x8 bb = *(const bf16x8*)(Wl + (size_t)wr * FDIM + ks * 32 + lk * 8);
            acc[t] = __builtin_amdgcn_mfma_f32_16x16x32_bf16(a, bb, acc[t], 0, 0, 0);
        }
    }
    #pragma unroll
    for (int ks = 0; ks < 4; ++ks) {
        bf16x8 a = *(const bf16x8*)(Xs + (arow * 16 + ((ks * 4 + lk) ^ (arow & 7))) * 8);
        #pragma unroll
        for (int t = 0; t < 4; ++t) {
            int wr = wcol * 64 + t * 16 + lr;
            bf16x8 bb = *(const bf16x8*)(Wr + (size_t)wr * FDIM + ks * 32 + lk * 8);
            acc[t] = __builtin_amdgcn_mfma_f32_16x16x32_bf16(a, bb, acc[t], 0, 0, 0);
        }
    }

    #pragma unroll
    for (int t = 0; t < 4; ++t) {
        int col = wcol * 64 + t * 16 + lr;
        float bc = bias[col];
        #pragma unroll
        for (int j = 0; j < 4; ++j) {
            int row = row0 + wrow * 16 + lk * 4 + j;
            if (row < n) {
                float v = acc[t][j] + bc;
                if (RELU) v = fmaxf(v, 0.f);
                out[(size_t)row * FDIM + col] = f2bf(v);
            }
        }
    }
}

// ---------------- MFMA head: out = h @ W3^T + b3 (fp32 out, 64 cols) ----------------

__global__ void final_mfma(const ushort* __restrict__ h, const ushort* __restrict__ W3,
                           const float* __restrict__ b3, float* __restrict__ out, int n) {
    __shared__ __align__(16) ushort Hs[32 * FDIM];
    const int row0 = blockIdx.x * 32;
    const int lane = threadIdx.x & 63;
    const int wid  = threadIdx.x >> 6;
    const int wrow = wid & 1;
    const int wcol = wid >> 1;

    const float4 z4 = make_float4(0.f, 0.f, 0.f, 0.f);
    #pragma unroll
    for (int i = 0; i < 2; ++i) {
        int s = threadIdx.x + i * 256;
        int r = s >> 4, cch = s & 15;
        int row = row0 + r;
        float4 vh = (row < n) ? *(const float4*)(h + (size_t)row * FDIM + cch * 8) : z4;
        int sc = cch ^ (r & 7);
        *(float4*)(Hs + (r * 16 + sc) * 8) = vh;
    }
    __syncthreads();

    const int lr = lane & 15;
    const int lk = lane >> 4;

    f32x4 acc[2];
    #pragma unroll
    for (int t = 0; t < 2; ++t) acc[t] = (f32x4){0.f, 0.f, 0.f, 0.f};

    const int arow = wrow * 16 + lr;
    #pragma unroll
    for (int ks = 0; ks < 4; ++ks) {
        bf16x8 a = *(const bf16x8*)(Hs + (arow * 16 + ((ks * 4 + lk) ^ (arow & 7))) * 8);
        #pragma unroll
        for (int t = 0; t < 2; ++t) {
            int wr = wcol * 32 + t * 16 + lr;
            bf16x8 bb = *(const bf16x8*)(W3 + (size_t)wr * FDIM + ks * 32 + lk * 8);
            acc[t] = __builtin_amdgcn_mfma_f32_16x16x32_bf16(a, bb, acc[t], 0, 0, 0);
        }
    }

    #pragma unroll
    for (int t = 0; t < 2; ++t) {
        int col = wcol * 32 + t * 16 + lr;
        float bc = b3[col];
        #pragma unroll
        for (int j = 0; j < 4; ++j) {
            int row = row0 + wrow * 16 + lk * 4 + j;
            if (row < n) out[(size_t)row * 64 + col] = acc[t][j] + bc;
        }
    }
}

// ---------------- launch ----------------

extern "C" void kernel_launch(void* const* d_in, const int* in_sizes, int n_in,
                              void* d_out, int out_size, void* d_ws, size_t ws_size,
                              hipStream_t stream) {
    const float* x   = (const float*)d_in[0];
    const int*   ei  = (const int*)d_in[1];
    const float* W1l = (const float*)d_in[2];
    const float* b1  = (const float*)d_in[3];
    const float* W1r = (const float*)d_in[4];
    const float* W2l = (const float*)d_in[5];
    const float* b2  = (const float*)d_in[6];
    const float* W2r = (const float*)d_in[7];
    const float* W3  = (const float*)d_in[8];
    const float* b3  = (const float*)d_in[9];
    float* out = (float*)d_out;

    const int N = in_sizes[0] / FDIM;   // 50000
    const int E = in_sizes[1] / 2;      // 800000
    const int* src = ei;
    const int* dst = ei + E;
    const int NBK = (N + 255) >> 8;     // 196

    char* ws = (char*)d_ws;
    size_t p = 0;
    auto alloc = [&](size_t bytes) {
        char* q = ws + p;
        p += (bytes + 255) & ~(size_t)255;
        return q;
    };
    int* bcnt    = (int*)alloc(256 * 4);
    int* bbase   = (int*)alloc(260 * 4);
    int* bcur    = (int*)alloc(256 * 4);
    uint2* pairs = (uint2*)alloc((size_t)E * 8);
    int* csr     = (int*)alloc((size_t)E * 4);
    int* off     = (int*)alloc((size_t)(N + 1) * 4);
    ushort* xb   = (ushort*)alloc((size_t)N * FDIM * 2);
    ushort* agb  = (ushort*)alloc((size_t)N * FDIM * 2);
    ushort* h1b  = (ushort*)alloc((size_t)N * FDIM * 2);
    ushort* wbuf = (ushort*)alloc(73728 * 2);
    ushort* w1l = wbuf, *w1r = wbuf + 16384, *w2l = wbuf + 32768,
           *w2r = wbuf + 49152, *w3 = wbuf + 65536;
    ushort* h2b = xb;   // xb dead after linear-1

    hipMemsetAsync(bcnt, 0, 256 * 4, stream);

    const int nx8   = N * FDIM / 8;         // 800000
    const int nconv = (nx8 + 255) / 256;    // 3125
    const int nhist = (E + 2047) / 2048;    // 391
    prep_kernel<<<nconv + 36 + nhist, 256, 0, stream>>>(
        x, xb, nx8, W1l, W1r, W2l, W2r, W3, wbuf, dst, E, bcnt, nconv);
    scan_buckets<<<1, 64, 0, stream>>>(bcnt, bbase, bcur, NBK);
    pair_scatter<<<(E + 2047) / 2048, 256, 0, stream>>>(src, dst, bcur, pairs, E);
    bucket_csr<<<NBK, 256, 0, stream>>>(pairs, bbase, off, csr, N);

    const int lgrid = (N + 31) / 32;
    // layer 1
    agg_kernel<<<(N + 3) / 4, 256, 0, stream>>>(xb, off, csr, agb, N);
    sage_linear_mfma<1><<<lgrid, 256, 0, stream>>>(agb, xb, w1l, w1r, b1, h1b, N);
    // layer 2
    agg_kernel<<<(N + 3) / 4, 256, 0, stream>>>(h1b, off, csr, agb, N);
    sage_linear_mfma<1><<<lgrid, 256, 0, stream>>>(agb, h1b, w2l, w2r, b2, h2b, N);
    // head
    final_mfma<<<lgrid, 256, 0, stream>>>(h2b, w3, b3, out, N);
}

// Round 4
// 181.297 us; speedup vs baseline: 2.8147x; 1.1015x over previous
//
#include <hip/hip_runtime.h>

#define FDIM 128

typedef __attribute__((ext_vector_type(8))) short bf16x8;
typedef __attribute__((ext_vector_type(4))) float f32x4;

static __device__ __forceinline__ ushort f2bf(float f) {
    uint u = __float_as_uint(f);
    uint r = (u + 0x7FFF + ((u >> 16) & 1)) >> 16;
    return (ushort)r;
}
static __device__ __forceinline__ uint packbf(float lo, float hi) {
    return (uint)f2bf(lo) | ((uint)f2bf(hi) << 16);
}
static __device__ __forceinline__ float bflo(uint v) { return __uint_as_float(v << 16); }
static __device__ __forceinline__ float bfhi(uint v) { return __uint_as_float(v & 0xFFFF0000u); }

// ---------------- prep: convert x + weights to bf16, bucket histogram ----------------

__global__ void prep_kernel(const float* __restrict__ x, ushort* __restrict__ xb, int nx8,
                            const float* __restrict__ W1l, const float* __restrict__ W1r,
                            const float* __restrict__ W2l, const float* __restrict__ W2r,
                            const float* __restrict__ W3, ushort* __restrict__ wbuf,
                            const int* __restrict__ dst, int E, int* __restrict__ bcnt,
                            int nconv) {
    const int b = blockIdx.x;
    const int tid = threadIdx.x;
    if (b < nconv) {
        int i = b * 256 + tid;
        if (i < nx8) {
            const float* s = x + (size_t)i * 8;
            float4 a = *(const float4*)(s);
            float4 c = *(const float4*)(s + 4);
            uint4 o;
            o.x = packbf(a.x, a.y); o.y = packbf(a.z, a.w);
            o.z = packbf(c.x, c.y); o.w = packbf(c.z, c.w);
            *(uint4*)(xb + (size_t)i * 8) = o;
        }
    } else if (b < nconv + 36) {
        int c = (b - nconv) * 256 + tid;      // 0..9215 chunks of 8
        const float* s; ushort* d;
        if (c < 2048)      { s = W1l + (size_t)c * 8;          d = wbuf + (size_t)c * 8; }
        else if (c < 4096) { s = W1r + (size_t)(c - 2048) * 8; d = wbuf + 16384 + (size_t)(c - 2048) * 8; }
        else if (c < 6144) { s = W2l + (size_t)(c - 4096) * 8; d = wbuf + 32768 + (size_t)(c - 4096) * 8; }
        else if (c < 8192) { s = W2r + (size_t)(c - 6144) * 8; d = wbuf + 49152 + (size_t)(c - 6144) * 8; }
        else               { s = W3  + (size_t)(c - 8192) * 8; d = wbuf + 65536 + (size_t)(c - 8192) * 8; }
        float4 a = *(const float4*)(s);
        float4 cc = *(const float4*)(s + 4);
        uint4 o;
        o.x = packbf(a.x, a.y); o.y = packbf(a.z, a.w);
        o.z = packbf(cc.x, cc.y); o.w = packbf(cc.z, cc.w);
        *(uint4*)d = o;
    } else {
        __shared__ int lh[256];
        int hb = b - nconv - 36;
        lh[tid] = 0;
        __syncthreads();
        #pragma unroll
        for (int k = 0; k < 8; ++k) {
            int e = hb * 2048 + k * 256 + tid;
            if (e < E) atomicAdd(&lh[dst[e] >> 8], 1);
        }
        __syncthreads();
        if (lh[tid]) atomicAdd(&bcnt[tid], lh[tid]);
    }
}

// ---------------- scan 196 bucket counts (1 block, 64 threads) ----------------

__global__ void scan_buckets(const int* __restrict__ bcnt, int* __restrict__ bbase,
                             int* __restrict__ bcur, int nb) {
    const int lane = threadIdx.x;
    const int i0 = lane * 4;
    int v0 = (i0 + 0 < nb) ? bcnt[i0 + 0] : 0;
    int v1 = (i0 + 1 < nb) ? bcnt[i0 + 1] : 0;
    int v2 = (i0 + 2 < nb) ? bcnt[i0 + 2] : 0;
    int v3 = (i0 + 3 < nb) ? bcnt[i0 + 3] : 0;
    int s = v0 + v1 + v2 + v3;
    int incl = s;
    #pragma unroll
    for (int d = 1; d < 64; d <<= 1) {
        int t = __shfl_up(incl, d);
        if (lane >= d) incl += t;
    }
    int excl = incl - s;
    int e0 = excl, e1 = excl + v0, e2 = e1 + v1, e3 = e2 + v2;
    if (i0 + 0 < nb) { bbase[i0 + 0] = e0; bcur[i0 + 0] = e0; }
    if (i0 + 1 < nb) { bbase[i0 + 1] = e1; bcur[i0 + 1] = e1; }
    if (i0 + 2 < nb) { bbase[i0 + 2] = e2; bcur[i0 + 2] = e2; }
    if (i0 + 3 < nb) { bbase[i0 + 3] = e3; bcur[i0 + 3] = e3; }
    int total = __shfl(incl, 63);
    if (lane == 0) bbase[nb] = total;
}

// ---------------- bin edges into bucket-contiguous packed (src | dlow<<24) ----------------

__global__ void pair_scatter(const int* __restrict__ src, const int* __restrict__ dst,
                             int* __restrict__ bcur, uint* __restrict__ pairs, int E) {
    __shared__ int lh[256];
    __shared__ int gb[256];
    const int tid = threadIdx.x;
    lh[tid] = 0;
    __syncthreads();
    int ss[8], dd[8], sl[8];
    #pragma unroll
    for (int k = 0; k < 8; ++k) {
        int e = blockIdx.x * 2048 + k * 256 + tid;
        if (e < E) {
            ss[k] = src[e];
            dd[k] = dst[e];
            sl[k] = atomicAdd(&lh[dd[k] >> 8], 1);
        } else dd[k] = -1;
    }
    __syncthreads();
    if (lh[tid]) gb[tid] = atomicAdd(&bcur[tid], lh[tid]);
    __syncthreads();
    #pragma unroll
    for (int k = 0; k < 8; ++k) {
        if (dd[k] >= 0)
            pairs[gb[dd[k] >> 8] + sl[k]] = (uint)ss[k] | ((uint)(dd[k] & 255) << 24);
    }
}

// ---------------- per-bucket CSR: LDS count/scan/scatter ----------------

__global__ void bucket_csr(const uint* __restrict__ pairs, const int* __restrict__ bbase,
                           int* __restrict__ off, int* __restrict__ csr, int N) {
    __shared__ int cnt[256];
    __shared__ int base[256];
    __shared__ int cur[256];
    const int b = blockIdx.x;
    const int tid = threadIdx.x;
    const int p0 = bbase[b], p1 = bbase[b + 1];
    cnt[tid] = 0;
    __syncthreads();
    for (int p = p0 + tid; p < p1; p += 256) atomicAdd(&cnt[pairs[p] >> 24], 1);
    __syncthreads();
    if (tid < 64) {
        int i0 = tid * 4;
        int v0 = cnt[i0], v1 = cnt[i0 + 1], v2 = cnt[i0 + 2], v3 = cnt[i0 + 3];
        int s = v0 + v1 + v2 + v3;
        int incl = s;
        #pragma unroll
        for (int d = 1; d < 64; d <<= 1) {
            int t = __shfl_up(incl, d);
            if (tid >= d) incl += t;
        }
        int excl = incl - s;
        base[i0] = excl; base[i0 + 1] = excl + v0;
        base[i0 + 2] = excl + v0 + v1; base[i0 + 3] = excl + v0 + v1 + v2;
        cur[i0] = base[i0]; cur[i0 + 1] = base[i0 + 1];
        cur[i0 + 2] = base[i0 + 2]; cur[i0 + 3] = base[i0 + 3];
    }
    __syncthreads();
    int node = (b << 8) + tid;
    if (node <= N) off[node] = p0 + base[tid];
    for (int p = p0 + tid; p < p1; p += 256) {
        uint e = pairs[p];
        int slot = atomicAdd(&cur[e >> 24], 1);
        csr[p0 + slot] = (int)(e & 0xFFFFFF);
    }
}

// ---------------- mean aggregation: wave/node, 4-deep unrolled gather ----------------

__global__ void agg_kernel(const ushort* __restrict__ feat, const int* __restrict__ off,
                           const int* __restrict__ csr, ushort* __restrict__ agg, int n) {
    int node = blockIdx.x * 4 + (threadIdx.x >> 6);
    if (node >= n) return;
    const int lane = threadIdx.x & 63;
    const int g = lane >> 4;       // neighbor slot 0..3
    const int c = lane & 15;       // 16B chunk 0..15
    const int j0 = off[node], j1 = off[node + 1];
    float a[8] = {0.f, 0.f, 0.f, 0.f, 0.f, 0.f, 0.f, 0.f};
    int j = j0 + g;
    for (; j + 12 < j1; j += 16) {
        int s0 = csr[j], s1 = csr[j + 4], s2 = csr[j + 8], s3 = csr[j + 12];
        uint4 v0 = *(const uint4*)(feat + (size_t)s0 * FDIM + c * 8);
        uint4 v1 = *(const uint4*)(feat + (size_t)s1 * FDIM + c * 8);
        uint4 v2 = *(const uint4*)(feat + (size_t)s2 * FDIM + c * 8);
        uint4 v3 = *(const uint4*)(feat + (size_t)s3 * FDIM + c * 8);
        a[0] += bflo(v0.x) + bflo(v1.x) + bflo(v2.x) + bflo(v3.x);
        a[1] += bfhi(v0.x) + bfhi(v1.x) + bfhi(v2.x) + bfhi(v3.x);
        a[2] += bflo(v0.y) + bflo(v1.y) + bflo(v2.y) + bflo(v3.y);
        a[3] += bfhi(v0.y) + bfhi(v1.y) + bfhi(v2.y) + bfhi(v3.y);
        a[4] += bflo(v0.z) + bflo(v1.z) + bflo(v2.z) + bflo(v3.z);
        a[5] += bfhi(v0.z) + bfhi(v1.z) + bfhi(v2.z) + bfhi(v3.z);
        a[6] += bflo(v0.w) + bflo(v1.w) + bflo(v2.w) + bflo(v3.w);
        a[7] += bfhi(v0.w) + bfhi(v1.w) + bfhi(v2.w) + bfhi(v3.w);
    }
    for (; j + 4 < j1; j += 8) {
        int s0 = csr[j], s1 = csr[j + 4];
        uint4 v0 = *(const uint4*)(feat + (size_t)s0 * FDIM + c * 8);
        uint4 v1 = *(const uint4*)(feat + (size_t)s1 * FDIM + c * 8);
        a[0] += bflo(v0.x) + bflo(v1.x); a[1] += bfhi(v0.x) + bfhi(v1.x);
        a[2] += bflo(v0.y) + bflo(v1.y); a[3] += bfhi(v0.y) + bfhi(v1.y);
        a[4] += bflo(v0.z) + bflo(v1.z); a[5] += bfhi(v0.z) + bfhi(v1.z);
        a[6] += bflo(v0.w) + bflo(v1.w); a[7] += bfhi(v0.w) + bfhi(v1.w);
    }
    for (; j < j1; j += 4) {
        int s0 = csr[j];
        uint4 v0 = *(const uint4*)(feat + (size_t)s0 * FDIM + c * 8);
        a[0] += bflo(v0.x); a[1] += bfhi(v0.x);
        a[2] += bflo(v0.y); a[3] += bfhi(v0.y);
        a[4] += bflo(v0.z); a[5] += bfhi(v0.z);
        a[6] += bflo(v0.w); a[7] += bfhi(v0.w);
    }
    #pragma unroll
    for (int k = 0; k < 8; ++k) {
        a[k] += __shfl_xor(a[k], 16);
        a[k] += __shfl_xor(a[k], 32);
    }
    if (g == 0) {
        float inv = 1.0f / fmaxf((float)(j1 - j0), 1.0f);
        uint4 o;
        o.x = packbf(a[0] * inv, a[1] * inv);
        o.y = packbf(a[2] * inv, a[3] * inv);
        o.z = packbf(a[4] * inv, a[5] * inv);
        o.w = packbf(a[6] * inv, a[7] * inv);
        *(uint4*)(agg + (size_t)node * FDIM + c * 8) = o;
    }
}

// ---------------- MFMA SAGE linear: out = relu(agg@Wl^T + x@Wr^T + b), bf16 ----------------

template<int RELU>
__global__ void sage_linear_mfma(const ushort* __restrict__ agg, const ushort* __restrict__ xin,
                                 const ushort* __restrict__ Wl, const ushort* __restrict__ Wr,
                                 const float* __restrict__ bias, ushort* __restrict__ out, int n) {
    __shared__ __align__(16) ushort As[32 * FDIM];
    __shared__ __align__(16) ushort Xs[32 * FDIM];
    const int row0 = blockIdx.x * 32;
    const int lane = threadIdx.x & 63;
    const int wid  = threadIdx.x >> 6;
    const int wrow = wid & 1;
    const int wcol = wid >> 1;

    const float4 z4 = make_float4(0.f, 0.f, 0.f, 0.f);
    #pragma unroll
    for (int i = 0; i < 2; ++i) {
        int s = threadIdx.x + i * 256;
        int r = s >> 4, cch = s & 15;
        int row = row0 + r;
        float4 va = z4, vx = z4;
        if (row < n) {
            va = *(const float4*)(agg + (size_t)row * FDIM + cch * 8);
            vx = *(const float4*)(xin + (size_t)row * FDIM + cch * 8);
        }
        int sc = cch ^ (r & 7);
        *(float4*)(As + (r * 16 + sc) * 8) = va;
        *(float4*)(Xs + (r * 16 + sc) * 8) = vx;
    }
    __syncthreads();

    const int lr = lane & 15;
    const int lk = lane >> 4;

    f32x4 acc[4];
    #pragma unroll
    for (int t = 0; t < 4; ++t) acc[t] = (f32x4){0.f, 0.f, 0.f, 0.f};

    const int arow = wrow * 16 + lr;
    #pragma unroll
    for (int ks = 0; ks < 4; ++ks) {
        bf16x8 a = *(const bf16x8*)(As + (arow * 16 + ((ks * 4 + lk) ^ (arow & 7))) * 8);
        #pragma unroll
        for (int t = 0; t < 4; ++t) {
            int wr = wcol * 64 + t * 16 + lr;
            bf16x8 bb = *(const bf16x8*)(Wl + (size_t)wr * FDIM + ks * 32 + lk * 8);
            acc[t] = __builtin_amdgcn_mfma_f32_16x16x32_bf16(a, bb, acc[t], 0, 0, 0);
        }
    }
    #pragma unroll
    for (int ks = 0; ks < 4; ++ks) {
        bf16x8 a = *(const bf16x8*)(Xs + (arow * 16 + ((ks * 4 + lk) ^ (arow & 7))) * 8);
        #pragma unroll
        for (int t = 0; t < 4; ++t) {
            int wr = wcol * 64 + t * 16 + lr;
            bf16x8 bb = *(const bf16x8*)(Wr + (size_t)wr * FDIM + ks * 32 + lk * 8);
            acc[t] = __builtin_amdgcn_mfma_f32_16x16x32_bf16(a, bb, acc[t], 0, 0, 0);
        }
    }

    #pragma unroll
    for (int t = 0; t < 4; ++t) {
        int col = wcol * 64 + t * 16 + lr;
        float bc = bias[col];
        #pragma unroll
        for (int j = 0; j < 4; ++j) {
            int row = row0 + wrow * 16 + lk * 4 + j;
            if (row < n) {
                float v = acc[t][j] + bc;
                if (RELU) v = fmaxf(v, 0.f);
                out[(size_t)row * FDIM + col] = f2bf(v);
            }
        }
    }
}

// ---------------- fused layer-2 linear + head ----------------
// h2 = relu(agg@W2l^T + h1@W2r^T + b2) kept in LDS (bf16, swizzled), then
// out = h2 @ W3^T + b3 written fp32.

__global__ void sage_linear2_head(const ushort* __restrict__ agg, const ushort* __restrict__ xin,
                                  const ushort* __restrict__ Wl, const ushort* __restrict__ Wr,
                                  const float* __restrict__ bias,
                                  const ushort* __restrict__ W3, const float* __restrict__ b3,
                                  float* __restrict__ out, int n) {
    __shared__ __align__(16) ushort As[32 * FDIM];
    __shared__ __align__(16) ushort Xs[32 * FDIM];
    const int row0 = blockIdx.x * 32;
    const int lane = threadIdx.x & 63;
    const int wid  = threadIdx.x >> 6;
    const int wrow = wid & 1;
    const int wcol = wid >> 1;

    const float4 z4 = make_float4(0.f, 0.f, 0.f, 0.f);
    #pragma unroll
    for (int i = 0; i < 2; ++i) {
        int s = threadIdx.x + i * 256;
        int r = s >> 4, cch = s & 15;
        int row = row0 + r;
        float4 va = z4, vx = z4;
        if (row < n) {
            va = *(const float4*)(agg + (size_t)row * FDIM + cch * 8);
            vx = *(const float4*)(xin + (size_t)row * FDIM + cch * 8);
        }
        int sc = cch ^ (r & 7);
        *(float4*)(As + (r * 16 + sc) * 8) = va;
        *(float4*)(Xs + (r * 16 + sc) * 8) = vx;
    }
    __syncthreads();

    const int lr = lane & 15;
    const int lk = lane >> 4;

    f32x4 acc[4];
    #pragma unroll
    for (int t = 0; t < 4; ++t) acc[t] = (f32x4){0.f, 0.f, 0.f, 0.f};

    const int arow = wrow * 16 + lr;
    #pragma unroll
    for (int ks = 0; ks < 4; ++ks) {
        bf16x8 a = *(const bf16x8*)(As + (arow * 16 + ((ks * 4 + lk) ^ (arow & 7))) * 8);
        #pragma unroll
        for (int t = 0; t < 4; ++t) {
            int wr = wcol * 64 + t * 16 + lr;
            bf16x8 bb = *(const bf16x8*)(Wl + (size_t)wr * FDIM + ks * 32 + lk * 8);
            acc[t] = __builtin_amdgcn_mfma_f32_16x16x32_bf16(a, bb, acc[t], 0, 0, 0);
        }
    }
    #pragma unroll
    for (int ks = 0; ks < 4; ++ks) {
        bf16x8 a = *(const bf16x8*)(Xs + (arow * 16 + ((ks * 4 + lk) ^ (arow & 7))) * 8);
        #pragma unroll
        for (int t = 0; t < 4; ++t) {
            int wr = wcol * 64 + t * 16 + lr;
            bf16x8 bb = *(const bf16x8*)(Wr + (size_t)wr * FDIM + ks * 32 + lk * 8);
            acc[t] = __builtin_amdgcn_mfma_f32_16x16x32_bf16(a, bb, acc[t], 0, 0, 0);
        }
    }

    // all waves done reading As/Xs -> write relu'd h2 tile (bf16) into As, swizzled
    __syncthreads();
    #pragma unroll
    for (int t = 0; t < 4; ++t) {
        int col = wcol * 64 + t * 16 + lr;
        float bc = bias[col];
        #pragma unroll
        for (int j = 0; j < 4; ++j) {
            int r = wrow * 16 + lk * 4 + j;
            float v = fmaxf(acc[t][j] + bc, 0.f);
            As[(r * 16 + ((col >> 3) ^ (r & 7))) * 8 + (col & 7)] = f2bf(v);
        }
    }
    __syncthreads();

    // head: out = h2 @ W3^T + b3
    f32x4 acc2[2];
    #pragma unroll
    for (int t = 0; t < 2; ++t) acc2[t] = (f32x4){0.f, 0.f, 0.f, 0.f};

    #pragma unroll
    for (int ks = 0; ks < 4; ++ks) {
        bf16x8 a = *(const bf16x8*)(As + (arow * 16 + ((ks * 4 + lk) ^ (arow & 7))) * 8);
        #pragma unroll
        for (int t = 0; t < 2; ++t) {
            int wr = wcol * 32 + t * 16 + lr;
            bf16x8 bb = *(const bf16x8*)(W3 + (size_t)wr * FDIM + ks * 32 + lk * 8);
            acc2[t] = __builtin_amdgcn_mfma_f32_16x16x32_bf16(a, bb, acc2[t], 0, 0, 0);
        }
    }

    #pragma unroll
    for (int t = 0; t < 2; ++t) {
        int col = wcol * 32 + t * 16 + lr;
        float bc = b3[col];
        #pragma unroll
        for (int j = 0; j < 4; ++j) {
            int row = row0 + wrow * 16 + lk * 4 + j;
            if (row < n) out[(size_t)row * 64 + col] = acc2[t][j] + bc;
        }
    }
}

// ---------------- launch ----------------

extern "C" void kernel_launch(void* const* d_in, const int* in_sizes, int n_in,
                              void* d_out, int out_size, void* d_ws, size_t ws_size,
                              hipStream_t stream) {
    const float* x   = (const float*)d_in[0];
    const int*   ei  = (const int*)d_in[1];
    const float* W1l = (const float*)d_in[2];
    const float* b1  = (const float*)d_in[3];
    const float* W1r = (const float*)d_in[4];
    const float* W2l = (const float*)d_in[5];
    const float* b2  = (const float*)d_in[6];
    const float* W2r = (const float*)d_in[7];
    const float* W3  = (const float*)d_in[8];
    const float* b3  = (const float*)d_in[9];
    float* out = (float*)d_out;

    const int N = in_sizes[0] / FDIM;   // 50000
    const int E = in_sizes[1] / 2;      // 800000
    const int* src = ei;
    const int* dst = ei + E;
    const int NBK = (N + 255) >> 8;     // 196

    char* ws = (char*)d_ws;
    size_t p = 0;
    auto alloc = [&](size_t bytes) {
        char* q = ws + p;
        p += (bytes + 255) & ~(size_t)255;
        return q;
    };
    int* bcnt    = (int*)alloc(256 * 4);
    int* bbase   = (int*)alloc(260 * 4);
    int* bcur    = (int*)alloc(256 * 4);
    uint* pairs  = (uint*)alloc((size_t)E * 4);
    int* csr     = (int*)alloc((size_t)E * 4);
    int* off     = (int*)alloc((size_t)(N + 1) * 4);
    ushort* xb   = (ushort*)alloc((size_t)N * FDIM * 2);
    ushort* agb  = (ushort*)alloc((size_t)N * FDIM * 2);
    ushort* h1b  = (ushort*)alloc((size_t)N * FDIM * 2);
    ushort* wbuf = (ushort*)alloc(73728 * 2);
    ushort* w1l = wbuf, *w1r = wbuf + 16384, *w2l = wbuf + 32768,
           *w2r = wbuf + 49152, *w3 = wbuf + 65536;

    hipMemsetAsync(bcnt, 0, 256 * 4, stream);

    const int nx8   = N * FDIM / 8;         // 800000
    const int nconv = (nx8 + 255) / 256;    // 3125
    const int nhist = (E + 2047) / 2048;    // 391
    prep_kernel<<<nconv + 36 + nhist, 256, 0, stream>>>(
        x, xb, nx8, W1l, W1r, W2l, W2r, W3, wbuf, dst, E, bcnt, nconv);
    scan_buckets<<<1, 64, 0, stream>>>(bcnt, bbase, bcur, NBK);
    pair_scatter<<<(E + 2047) / 2048, 256, 0, stream>>>(src, dst, bcur, pairs, E);
    bucket_csr<<<NBK, 256, 0, stream>>>(pairs, bbase, off, csr, N);

    const int lgrid = (N + 31) / 32;
    // layer 1
    agg_kernel<<<(N + 3) / 4, 256, 0, stream>>>(xb, off, csr, agb, N);
    sage_linear_mfma<1><<<lgrid, 256, 0, stream>>>(agb, xb, w1l, w1r, b1, h1b, N);
    // layer 2 + head (fused)
    agg_kernel<<<(N + 3) / 4, 256, 0, stream>>>(h1b, off, csr, agb, N);
    sage_linear2_head<<<lgrid, 256, 0, stream>>>(agb, h1b, w2l, w2r, b2, w3, b3, out, N);
}

// Round 5
// 169.673 us; speedup vs baseline: 3.0076x; 1.0685x over previous
//
#include <hip/hip_runtime.h>

#define FDIM 128

typedef __attribute__((ext_vector_type(8))) short bf16x8;
typedef __attribute__((ext_vector_type(4))) float f32x4;

static __device__ __forceinline__ ushort f2bf(float f) {
    uint u = __float_as_uint(f);
    uint r = (u + 0x7FFF + ((u >> 16) & 1)) >> 16;
    return (ushort)r;
}
static __device__ __forceinline__ uint packbf(float lo, float hi) {
    return (uint)f2bf(lo) | ((uint)f2bf(hi) << 16);
}
static __device__ __forceinline__ float bflo(uint v) { return __uint_as_float(v << 16); }
static __device__ __forceinline__ float bfhi(uint v) { return __uint_as_float(v & 0xFFFF0000u); }

// ---------------- prep: convert x + weights to bf16, bucket histogram ----------------

__global__ void prep_kernel(const float* __restrict__ x, ushort* __restrict__ xb, int nx8,
                            const float* __restrict__ W1l, const float* __restrict__ W1r,
                            const float* __restrict__ W2l, const float* __restrict__ W2r,
                            const float* __restrict__ W3, ushort* __restrict__ wbuf,
                            const int* __restrict__ dst, int E, int* __restrict__ bcnt,
                            int nconv) {
    const int b = blockIdx.x;
    const int tid = threadIdx.x;
    if (b < nconv) {
        int i = b * 256 + tid;
        if (i < nx8) {
            const float* s = x + (size_t)i * 8;
            float4 a = *(const float4*)(s);
            float4 c = *(const float4*)(s + 4);
            uint4 o;
            o.x = packbf(a.x, a.y); o.y = packbf(a.z, a.w);
            o.z = packbf(c.x, c.y); o.w = packbf(c.z, c.w);
            *(uint4*)(xb + (size_t)i * 8) = o;
        }
    } else if (b < nconv + 36) {
        int c = (b - nconv) * 256 + tid;      // 0..9215 chunks of 8
        const float* s; ushort* d;
        if (c < 2048)      { s = W1l + (size_t)c * 8;          d = wbuf + (size_t)c * 8; }
        else if (c < 4096) { s = W1r + (size_t)(c - 2048) * 8; d = wbuf + 16384 + (size_t)(c - 2048) * 8; }
        else if (c < 6144) { s = W2l + (size_t)(c - 4096) * 8; d = wbuf + 32768 + (size_t)(c - 4096) * 8; }
        else if (c < 8192) { s = W2r + (size_t)(c - 6144) * 8; d = wbuf + 49152 + (size_t)(c - 6144) * 8; }
        else               { s = W3  + (size_t)(c - 8192) * 8; d = wbuf + 65536 + (size_t)(c - 8192) * 8; }
        float4 a = *(const float4*)(s);
        float4 cc = *(const float4*)(s + 4);
        uint4 o;
        o.x = packbf(a.x, a.y); o.y = packbf(a.z, a.w);
        o.z = packbf(cc.x, cc.y); o.w = packbf(cc.z, cc.w);
        *(uint4*)d = o;
    } else {
        __shared__ int lh[256];
        int hb = b - nconv - 36;
        lh[tid] = 0;
        __syncthreads();
        #pragma unroll
        for (int k = 0; k < 8; ++k) {
            int e = hb * 2048 + k * 256 + tid;
            if (e < E) atomicAdd(&lh[dst[e] >> 8], 1);
        }
        __syncthreads();
        if (lh[tid]) atomicAdd(&bcnt[tid], lh[tid]);
    }
}

// ---------------- scan 196 bucket counts (1 block, 64 threads) ----------------

__global__ void scan_buckets(const int* __restrict__ bcnt, int* __restrict__ bbase,
                             int* __restrict__ bcur, int nb) {
    const int lane = threadIdx.x;
    const int i0 = lane * 4;
    int v0 = (i0 + 0 < nb) ? bcnt[i0 + 0] : 0;
    int v1 = (i0 + 1 < nb) ? bcnt[i0 + 1] : 0;
    int v2 = (i0 + 2 < nb) ? bcnt[i0 + 2] : 0;
    int v3 = (i0 + 3 < nb) ? bcnt[i0 + 3] : 0;
    int s = v0 + v1 + v2 + v3;
    int incl = s;
    #pragma unroll
    for (int d = 1; d < 64; d <<= 1) {
        int t = __shfl_up(incl, d);
        if (lane >= d) incl += t;
    }
    int excl = incl - s;
    int e0 = excl, e1 = excl + v0, e2 = e1 + v1, e3 = e2 + v2;
    if (i0 + 0 < nb) { bbase[i0 + 0] = e0; bcur[i0 + 0] = e0; }
    if (i0 + 1 < nb) { bbase[i0 + 1] = e1; bcur[i0 + 1] = e1; }
    if (i0 + 2 < nb) { bbase[i0 + 2] = e2; bcur[i0 + 2] = e2; }
    if (i0 + 3 < nb) { bbase[i0 + 3] = e3; bcur[i0 + 3] = e3; }
    int total = __shfl(incl, 63);
    if (lane == 0) bbase[nb] = total;
}

// ---------------- bin edges into bucket-contiguous packed (src | dlow<<24) ----------------

__global__ void pair_scatter(const int* __restrict__ src, const int* __restrict__ dst,
                             int* __restrict__ bcur, uint* __restrict__ pairs, int E) {
    __shared__ int lh[256];
    __shared__ int gb[256];
    const int tid = threadIdx.x;
    lh[tid] = 0;
    __syncthreads();
    int ss[8], dd[8], sl[8];
    #pragma unroll
    for (int k = 0; k < 8; ++k) {
        int e = blockIdx.x * 2048 + k * 256 + tid;
        if (e < E) {
            ss[k] = src[e];
            dd[k] = dst[e];
            sl[k] = atomicAdd(&lh[dd[k] >> 8], 1);
        } else dd[k] = -1;
    }
    __syncthreads();
    if (lh[tid]) gb[tid] = atomicAdd(&bcur[tid], lh[tid]);
    __syncthreads();
    #pragma unroll
    for (int k = 0; k < 8; ++k) {
        if (dd[k] >= 0)
            pairs[gb[dd[k] >> 8] + sl[k]] = (uint)ss[k] | ((uint)(dd[k] & 255) << 24);
    }
}

// ---------------- per-bucket CSR: LDS count/scan/scatter ----------------

__global__ void bucket_csr(const uint* __restrict__ pairs, const int* __restrict__ bbase,
                           int* __restrict__ off, int* __restrict__ csr, int N) {
    __shared__ int cnt[256];
    __shared__ int base[256];
    __shared__ int cur[256];
    const int b = blockIdx.x;
    const int tid = threadIdx.x;
    const int p0 = bbase[b], p1 = bbase[b + 1];
    cnt[tid] = 0;
    __syncthreads();
    for (int p = p0 + tid; p < p1; p += 256) atomicAdd(&cnt[pairs[p] >> 24], 1);
    __syncthreads();
    if (tid < 64) {
        int i0 = tid * 4;
        int v0 = cnt[i0], v1 = cnt[i0 + 1], v2 = cnt[i0 + 2], v3 = cnt[i0 + 3];
        int s = v0 + v1 + v2 + v3;
        int incl = s;
        #pragma unroll
        for (int d = 1; d < 64; d <<= 1) {
            int t = __shfl_up(incl, d);
            if (tid >= d) incl += t;
        }
        int excl = incl - s;
        base[i0] = excl; base[i0 + 1] = excl + v0;
        base[i0 + 2] = excl + v0 + v1; base[i0 + 3] = excl + v0 + v1 + v2;
        cur[i0] = base[i0]; cur[i0 + 1] = base[i0 + 1];
        cur[i0 + 2] = base[i0 + 2]; cur[i0 + 3] = base[i0 + 3];
    }
    __syncthreads();
    int node = (b << 8) + tid;
    if (node <= N) off[node] = p0 + base[tid];
    for (int p = p0 + tid; p < p1; p += 256) {
        uint e = pairs[p];
        int slot = atomicAdd(&cur[e >> 24], 1);
        csr[p0 + slot] = (int)(e & 0xFFFFFF);
    }
}

// ---------------- fused SAGE layer: gather-mean -> LDS, MFMA linear(s) ----------------
// block = 256 thr (4 waves), 32 nodes/block. Wave w gathers nodes w*8..w*8+7
// (quarter-wave slots, 4-deep unroll), writes mean rows bf16 swizzled into As.
// Xs = self rows staged cooperatively. Then MFMA: relu(As@Wl^T + Xs@Wr^T + b).
// HEAD=0: write bf16 h. HEAD=1: keep h in LDS, second MFMA with W3 -> fp32 out.

template<int HEAD>
__global__ void fused_sage(const ushort* __restrict__ feat, const int* __restrict__ off,
                           const int* __restrict__ csr,
                           const ushort* __restrict__ Wl, const ushort* __restrict__ Wr,
                           const float* __restrict__ bias,
                           const ushort* __restrict__ W3, const float* __restrict__ b3,
                           ushort* __restrict__ hout, float* __restrict__ fout, int n) {
    __shared__ __align__(16) ushort As[32 * FDIM];
    __shared__ __align__(16) ushort Xs[32 * FDIM];
    const int row0 = blockIdx.x * 32;
    const int lane = threadIdx.x & 63;
    const int wid  = threadIdx.x >> 6;

    // stage self rows (coalesced)
    const float4 z4 = make_float4(0.f, 0.f, 0.f, 0.f);
    #pragma unroll
    for (int i = 0; i < 2; ++i) {
        int s = threadIdx.x + i * 256;
        int r = s >> 4, cch = s & 15;
        int row = row0 + r;
        float4 vx = (row < n) ? *(const float4*)(feat + (size_t)row * FDIM + cch * 8) : z4;
        *(float4*)(Xs + (r * 16 + (cch ^ (r & 7))) * 8) = vx;
    }

    // gather-mean 8 nodes per wave into As
    const int g = lane >> 4;       // neighbor slot 0..3
    const int c = lane & 15;       // 16B chunk 0..15
    for (int i = 0; i < 8; ++i) {
        const int r = wid * 8 + i;
        const int node = row0 + r;
        float a[8] = {0.f, 0.f, 0.f, 0.f, 0.f, 0.f, 0.f, 0.f};
        float inv = 0.f;
        if (node < n) {
            const int j0 = off[node], j1 = off[node + 1];
            int j = j0 + g;
            for (; j + 12 < j1; j += 16) {
                int s0 = csr[j], s1 = csr[j + 4], s2 = csr[j + 8], s3 = csr[j + 12];
                uint4 v0 = *(const uint4*)(feat + (size_t)s0 * FDIM + c * 8);
                uint4 v1 = *(const uint4*)(feat + (size_t)s1 * FDIM + c * 8);
                uint4 v2 = *(const uint4*)(feat + (size_t)s2 * FDIM + c * 8);
                uint4 v3 = *(const uint4*)(feat + (size_t)s3 * FDIM + c * 8);
                a[0] += bflo(v0.x) + bflo(v1.x) + bflo(v2.x) + bflo(v3.x);
                a[1] += bfhi(v0.x) + bfhi(v1.x) + bfhi(v2.x) + bfhi(v3.x);
                a[2] += bflo(v0.y) + bflo(v1.y) + bflo(v2.y) + bflo(v3.y);
                a[3] += bfhi(v0.y) + bfhi(v1.y) + bfhi(v2.y) + bfhi(v3.y);
                a[4] += bflo(v0.z) + bflo(v1.z) + bflo(v2.z) + bflo(v3.z);
                a[5] += bfhi(v0.z) + bfhi(v1.z) + bfhi(v2.z) + bfhi(v3.z);
                a[6] += bflo(v0.w) + bflo(v1.w) + bflo(v2.w) + bflo(v3.w);
                a[7] += bfhi(v0.w) + bfhi(v1.w) + bfhi(v2.w) + bfhi(v3.w);
            }
            for (; j + 4 < j1; j += 8) {
                int s0 = csr[j], s1 = csr[j + 4];
                uint4 v0 = *(const uint4*)(feat + (size_t)s0 * FDIM + c * 8);
                uint4 v1 = *(const uint4*)(feat + (size_t)s1 * FDIM + c * 8);
                a[0] += bflo(v0.x) + bflo(v1.x); a[1] += bfhi(v0.x) + bfhi(v1.x);
                a[2] += bflo(v0.y) + bflo(v1.y); a[3] += bfhi(v0.y) + bfhi(v1.y);
                a[4] += bflo(v0.z) + bflo(v1.z); a[5] += bfhi(v0.z) + bfhi(v1.z);
                a[6] += bflo(v0.w) + bflo(v1.w); a[7] += bfhi(v0.w) + bfhi(v1.w);
            }
            for (; j < j1; j += 4) {
                int s0 = csr[j];
                uint4 v0 = *(const uint4*)(feat + (size_t)s0 * FDIM + c * 8);
                a[0] += bflo(v0.x); a[1] += bfhi(v0.x);
                a[2] += bflo(v0.y); a[3] += bfhi(v0.y);
                a[4] += bflo(v0.z); a[5] += bfhi(v0.z);
                a[6] += bflo(v0.w); a[7] += bfhi(v0.w);
            }
            inv = 1.0f / fmaxf((float)(j1 - j0), 1.0f);
        }
        #pragma unroll
        for (int k = 0; k < 8; ++k) {
            a[k] += __shfl_xor(a[k], 16);
            a[k] += __shfl_xor(a[k], 32);
        }
        if (g == 0) {
            uint4 o;
            o.x = packbf(a[0] * inv, a[1] * inv);
            o.y = packbf(a[2] * inv, a[3] * inv);
            o.z = packbf(a[4] * inv, a[5] * inv);
            o.w = packbf(a[6] * inv, a[7] * inv);
            *(uint4*)(As + (r * 16 + (c ^ (r & 7))) * 8) = o;
        }
    }
    __syncthreads();

    const int wrow = wid & 1;
    const int wcol = wid >> 1;
    const int lr = lane & 15;
    const int lk = lane >> 4;

    f32x4 acc[4];
    #pragma unroll
    for (int t = 0; t < 4; ++t) acc[t] = (f32x4){0.f, 0.f, 0.f, 0.f};

    const int arow = wrow * 16 + lr;
    #pragma unroll
    for (int ks = 0; ks < 4; ++ks) {
        bf16x8 a = *(const bf16x8*)(As + (arow * 16 + ((ks * 4 + lk) ^ (arow & 7))) * 8);
        #pragma unroll
        for (int t = 0; t < 4; ++t) {
            int wr = wcol * 64 + t * 16 + lr;
            bf16x8 bb = *(const bf16x8*)(Wl + (size_t)wr * FDIM + ks * 32 + lk * 8);
            acc[t] = __builtin_amdgcn_mfma_f32_16x16x32_bf16(a, bb, acc[t], 0, 0, 0);
        }
    }
    #pragma unroll
    for (int ks = 0; ks < 4; ++ks) {
        bf16x8 a = *(const bf16x8*)(Xs + (arow * 16 + ((ks * 4 + lk) ^ (arow & 7))) * 8);
        #pragma unroll
        for (int t = 0; t < 4; ++t) {
            int wr = wcol * 64 + t * 16 + lr;
            bf16x8 bb = *(const bf16x8*)(Wr + (size_t)wr * FDIM + ks * 32 + lk * 8);
            acc[t] = __builtin_amdgcn_mfma_f32_16x16x32_bf16(a, bb, acc[t], 0, 0, 0);
        }
    }

    if (HEAD == 0) {
        #pragma unroll
        for (int t = 0; t < 4; ++t) {
            int col = wcol * 64 + t * 16 + lr;
            float bc = bias[col];
            #pragma unroll
            for (int j = 0; j < 4; ++j) {
                int row = row0 + wrow * 16 + lk * 4 + j;
                if (row < n) {
                    float v = fmaxf(acc[t][j] + bc, 0.f);
                    hout[(size_t)row * FDIM + col] = f2bf(v);
                }
            }
        }
    } else {
        // write relu'd h2 tile into As (swizzled), then head MFMA
        __syncthreads();
        #pragma unroll
        for (int t = 0; t < 4; ++t) {
            int col = wcol * 64 + t * 16 + lr;
            float bc = bias[col];
            #pragma unroll
            for (int j = 0; j < 4; ++j) {
                int r = wrow * 16 + lk * 4 + j;
                float v = fmaxf(acc[t][j] + bc, 0.f);
                As[(r * 16 + ((col >> 3) ^ (r & 7))) * 8 + (col & 7)] = f2bf(v);
            }
        }
        __syncthreads();

        f32x4 acc2[2];
        #pragma unroll
        for (int t = 0; t < 2; ++t) acc2[t] = (f32x4){0.f, 0.f, 0.f, 0.f};

        #pragma unroll
        for (int ks = 0; ks < 4; ++ks) {
            bf16x8 a = *(const bf16x8*)(As + (arow * 16 + ((ks * 4 + lk) ^ (arow & 7))) * 8);
            #pragma unroll
            for (int t = 0; t < 2; ++t) {
                int wr = wcol * 32 + t * 16 + lr;
                bf16x8 bb = *(const bf16x8*)(W3 + (size_t)wr * FDIM + ks * 32 + lk * 8);
                acc2[t] = __builtin_amdgcn_mfma_f32_16x16x32_bf16(a, bb, acc2[t], 0, 0, 0);
            }
        }

        #pragma unroll
        for (int t = 0; t < 2; ++t) {
            int col = wcol * 32 + t * 16 + lr;
            float bc = b3[col];
            #pragma unroll
            for (int j = 0; j < 4; ++j) {
                int row = row0 + wrow * 16 + lk * 4 + j;
                if (row < n) fout[(size_t)row * 64 + col] = acc2[t][j] + bc;
            }
        }
    }
}

// ---------------- launch ----------------

extern "C" void kernel_launch(void* const* d_in, const int* in_sizes, int n_in,
                              void* d_out, int out_size, void* d_ws, size_t ws_size,
                              hipStream_t stream) {
    const float* x   = (const float*)d_in[0];
    const int*   ei  = (const int*)d_in[1];
    const float* W1l = (const float*)d_in[2];
    const float* b1  = (const float*)d_in[3];
    const float* W1r = (const float*)d_in[4];
    const float* W2l = (const float*)d_in[5];
    const float* b2  = (const float*)d_in[6];
    const float* W2r = (const float*)d_in[7];
    const float* W3  = (const float*)d_in[8];
    const float* b3  = (const float*)d_in[9];
    float* out = (float*)d_out;

    const int N = in_sizes[0] / FDIM;   // 50000
    const int E = in_sizes[1] / 2;      // 800000
    const int* src = ei;
    const int* dst = ei + E;
    const int NBK = (N + 255) >> 8;     // 196

    char* ws = (char*)d_ws;
    size_t p = 0;
    auto alloc = [&](size_t bytes) {
        char* q = ws + p;
        p += (bytes + 255) & ~(size_t)255;
        return q;
    };
    int* bcnt    = (int*)alloc(256 * 4);
    int* bbase   = (int*)alloc(260 * 4);
    int* bcur    = (int*)alloc(256 * 4);
    uint* pairs  = (uint*)alloc((size_t)E * 4);
    int* csr     = (int*)alloc((size_t)E * 4);
    int* off     = (int*)alloc((size_t)(N + 1) * 4);
    ushort* xb   = (ushort*)alloc((size_t)N * FDIM * 2);
    ushort* h1b  = (ushort*)alloc((size_t)N * FDIM * 2);
    ushort* wbuf = (ushort*)alloc(73728 * 2);
    ushort* w1l = wbuf, *w1r = wbuf + 16384, *w2l = wbuf + 32768,
           *w2r = wbuf + 49152, *w3 = wbuf + 65536;

    hipMemsetAsync(bcnt, 0, 256 * 4, stream);

    const int nx8   = N * FDIM / 8;         // 800000
    const int nconv = (nx8 + 255) / 256;    // 3125
    const int nhist = (E + 2047) / 2048;    // 391
    prep_kernel<<<nconv + 36 + nhist, 256, 0, stream>>>(
        x, xb, nx8, W1l, W1r, W2l, W2r, W3, wbuf, dst, E, bcnt, nconv);
    scan_buckets<<<1, 64, 0, stream>>>(bcnt, bbase, bcur, NBK);
    pair_scatter<<<(E + 2047) / 2048, 256, 0, stream>>>(src, dst, bcur, pairs, E);
    bucket_csr<<<NBK, 256, 0, stream>>>(pairs, bbase, off, csr, N);

    const int lgrid = (N + 31) / 32;
    fused_sage<0><<<lgrid, 256, 0, stream>>>(xb, off, csr, w1l, w1r, b1,
                                             (const ushort*)nullptr, (const float*)nullptr,
                                             h1b, (float*)nullptr, N);
    fused_sage<1><<<lgrid, 256, 0, stream>>>(h1b, off, csr, w2l, w2r, b2,
                                             w3, b3, (ushort*)nullptr, out, N);
}